// Round 1
// baseline (159.115 us; speedup 1.0000x reference)
//
#include <hip/hip_runtime.h>
#include <hip/hip_bf16.h>
#include <math.h>

// ws layout (floats)
#define OFF_AI 0        // A_i  [48][40]  h coeff on image
#define OFF_AT 1920     // A_t  [48][20]  h coeff on text
#define OFF_CH 2880     // c_h  [48]
#define OFF_GI 2928     // G_i  [48][40]  gate coeff on image
#define OFF_GT 4848     // G_t  [48][20]  gate coeff on text
#define OFF_CG 5808     // c_g  [48]
#define WS_FLOATS 5856

// Fold the linear prefix (v-projections + m1/gate input halves) into small
// per-input matrices. Runs as 1 block, trivial cost, every call (deterministic).
__global__ void fold_kernel(
    const float* __restrict__ Wiv, const float* __restrict__ biv,
    const float* __restrict__ Wtv, const float* __restrict__ btv,
    const float* __restrict__ Wisv, const float* __restrict__ bisv,
    const float* __restrict__ Wtsv, const float* __restrict__ btsv,
    const float* __restrict__ Wm1, const float* __restrict__ bm1,
    const float* __restrict__ Wg, const float* __restrict__ bg,
    float* __restrict__ ws) {
  const int t = threadIdx.x;
  const int nt = blockDim.x;

  // A_i[o][j] = sum_{k<48} Wm1[o][48+k]*Wtv[k][j] + sum_{k<24} Wm1[o][96+k]*Wisv[k][j]
  for (int idx = t; idx < 48 * 40; idx += nt) {
    int o = idx / 40, j = idx % 40;
    float acc = 0.f;
    for (int k = 0; k < 48; ++k) acc += Wm1[o * 144 + 48 + k] * Wtv[k * 40 + j];
    for (int k = 0; k < 24; ++k) acc += Wm1[o * 144 + 96 + k] * Wisv[k * 40 + j];
    ws[OFF_AI + idx] = acc;
  }
  // A_t[o][j] = sum_{k<48} Wm1[o][k]*Wiv[k][j] + sum_{k<24} Wm1[o][120+k]*Wtsv[k][j]
  for (int idx = t; idx < 48 * 20; idx += nt) {
    int o = idx / 20, j = idx % 20;
    float acc = 0.f;
    for (int k = 0; k < 48; ++k) acc += Wm1[o * 144 + k] * Wiv[k * 20 + j];
    for (int k = 0; k < 24; ++k) acc += Wm1[o * 144 + 120 + k] * Wtsv[k * 20 + j];
    ws[OFF_AT + idx] = acc;
  }
  // c_h[o] = bm1[o] + Wm1[o,:48]·biv + Wm1[o,48:96]·btv + Wm1[o,96:120]·bisv + Wm1[o,120:144]·btsv
  for (int o = t; o < 48; o += nt) {
    float acc = bm1[o];
    for (int k = 0; k < 48; ++k) acc += Wm1[o * 144 + k] * biv[k];
    for (int k = 0; k < 48; ++k) acc += Wm1[o * 144 + 48 + k] * btv[k];
    for (int k = 0; k < 24; ++k) acc += Wm1[o * 144 + 96 + k] * bisv[k];
    for (int k = 0; k < 24; ++k) acc += Wm1[o * 144 + 120 + k] * btsv[k];
    ws[OFF_CH + o] = acc;
  }
  // G_i[o][j] = sum_{k<48} Wg[o][48+k]*Wtv[k][j]   (txt_cross depends on image)
  for (int idx = t; idx < 48 * 40; idx += nt) {
    int o = idx / 40, j = idx % 40;
    float acc = 0.f;
    for (int k = 0; k < 48; ++k) acc += Wg[o * 96 + 48 + k] * Wtv[k * 40 + j];
    ws[OFF_GI + idx] = acc;
  }
  // G_t[o][j] = sum_{k<48} Wg[o][k]*Wiv[k][j]      (img_cross depends on text)
  for (int idx = t; idx < 48 * 20; idx += nt) {
    int o = idx / 20, j = idx % 20;
    float acc = 0.f;
    for (int k = 0; k < 48; ++k) acc += Wg[o * 96 + k] * Wiv[k * 20 + j];
    ws[OFF_GT + idx] = acc;
  }
  // c_g[o] = bg[o] + Wg[o,:48]·biv + Wg[o,48:96]·btv
  for (int o = t; o < 48; o += nt) {
    float acc = bg[o];
    for (int k = 0; k < 48; ++k) acc += Wg[o * 96 + k] * biv[k];
    for (int k = 0; k < 48; ++k) acc += Wg[o * 96 + 48 + k] * btv[k];
    ws[OFF_CG + o] = acc;
  }
}

__global__ __launch_bounds__(256) void fused_main(
    const float* __restrict__ img, const float* __restrict__ txt,
    const float* __restrict__ ws, const float* __restrict__ Wm2g,
    const float* __restrict__ bm2g, float* __restrict__ out, int nrows) {
  __shared__ float sm[WS_FLOATS + 48 * 48 + 48];
  for (int i = threadIdx.x; i < WS_FLOATS; i += 256) sm[i] = ws[i];
  for (int i = threadIdx.x; i < 48 * 48; i += 256) sm[WS_FLOATS + i] = Wm2g[i];
  if (threadIdx.x < 48) sm[WS_FLOATS + 48 * 48 + threadIdx.x] = bm2g[threadIdx.x];
  __syncthreads();

  const float* sAi = sm + OFF_AI;
  const float* sAt = sm + OFF_AT;
  const float* sch = sm + OFF_CH;
  const float* sGi = sm + OFF_GI;
  const float* sGt = sm + OFF_GT;
  const float* scg = sm + OFF_CG;
  const float* sW2 = sm + WS_FLOATS;
  const float* sb2 = sm + WS_FLOATS + 48 * 48;

  const int row = blockIdx.x * 256 + threadIdx.x;
  if (row >= nrows) return;

  float x[40], tt[20];
  {
    const float4* p = reinterpret_cast<const float4*>(img + (size_t)row * 40);
#pragma unroll
    for (int j = 0; j < 10; ++j) {
      float4 v = p[j];
      x[4 * j + 0] = v.x; x[4 * j + 1] = v.y; x[4 * j + 2] = v.z; x[4 * j + 3] = v.w;
    }
    const float4* q = reinterpret_cast<const float4*>(txt + (size_t)row * 20);
#pragma unroll
    for (int j = 0; j < 5; ++j) {
      float4 v = q[j];
      tt[4 * j + 0] = v.x; tt[4 * j + 1] = v.y; tt[4 * j + 2] = v.z; tt[4 * j + 3] = v.w;
    }
  }

  // h = relu(A_i x + A_t t + c_h)
  float h[48];
#pragma unroll 2
  for (int o = 0; o < 48; ++o) {
    float acc = sch[o];
    const float4* a = reinterpret_cast<const float4*>(sAi + o * 40);
#pragma unroll
    for (int j = 0; j < 10; ++j) {
      float4 w = a[j];
      acc = fmaf(w.x, x[4 * j + 0], acc);
      acc = fmaf(w.y, x[4 * j + 1], acc);
      acc = fmaf(w.z, x[4 * j + 2], acc);
      acc = fmaf(w.w, x[4 * j + 3], acc);
    }
    const float4* b = reinterpret_cast<const float4*>(sAt + o * 20);
#pragma unroll
    for (int j = 0; j < 5; ++j) {
      float4 w = b[j];
      acc = fmaf(w.x, tt[4 * j + 0], acc);
      acc = fmaf(w.y, tt[4 * j + 1], acc);
      acc = fmaf(w.z, tt[4 * j + 2], acc);
      acc = fmaf(w.w, tt[4 * j + 3], acc);
    }
    h[o] = fmaxf(acc, 0.f);
  }

  float* orow = out + (size_t)row * 48;
#pragma unroll 1
  for (int o4 = 0; o4 < 12; ++o4) {
    float res[4];
#pragma unroll
    for (int oo = 0; oo < 4; ++oo) {
      const int o = o4 * 4 + oo;
      // fused = relu(Wm2 h + bm2)
      float f = sb2[o];
      const float4* w2 = reinterpret_cast<const float4*>(sW2 + o * 48);
#pragma unroll
      for (int k = 0; k < 12; ++k) {
        float4 w = w2[k];
        f = fmaf(w.x, h[4 * k + 0], f);
        f = fmaf(w.y, h[4 * k + 1], f);
        f = fmaf(w.z, h[4 * k + 2], f);
        f = fmaf(w.w, h[4 * k + 3], f);
      }
      f = fmaxf(f, 0.f);
      // gate = sigmoid(G_i x + G_t t + c_g)
      float g = scg[o];
      const float4* gi = reinterpret_cast<const float4*>(sGi + o * 40);
#pragma unroll
      for (int j = 0; j < 10; ++j) {
        float4 w = gi[j];
        g = fmaf(w.x, x[4 * j + 0], g);
        g = fmaf(w.y, x[4 * j + 1], g);
        g = fmaf(w.z, x[4 * j + 2], g);
        g = fmaf(w.w, x[4 * j + 3], g);
      }
      const float4* gt = reinterpret_cast<const float4*>(sGt + o * 20);
#pragma unroll
      for (int j = 0; j < 5; ++j) {
        float4 w = gt[j];
        g = fmaf(w.x, tt[4 * j + 0], g);
        g = fmaf(w.y, tt[4 * j + 1], g);
        g = fmaf(w.z, tt[4 * j + 2], g);
        g = fmaf(w.w, tt[4 * j + 3], g);
      }
      g = 1.0f / (1.0f + __expf(-g));
      res[oo] = f * g;
    }
    float4 v;
    v.x = res[0]; v.y = res[1]; v.z = res[2]; v.w = res[3];
    reinterpret_cast<float4*>(orow)[o4] = v;
  }
}

extern "C" void kernel_launch(void* const* d_in, const int* in_sizes, int n_in,
                              void* d_out, int out_size, void* d_ws, size_t ws_size,
                              hipStream_t stream) {
  const float* img  = (const float*)d_in[0];
  const float* txt  = (const float*)d_in[1];
  const float* Wiv  = (const float*)d_in[6];
  const float* biv  = (const float*)d_in[7];
  const float* Wtv  = (const float*)d_in[12];
  const float* btv  = (const float*)d_in[13];
  const float* Wisv = (const float*)d_in[18];
  const float* bisv = (const float*)d_in[19];
  const float* Wtsv = (const float*)d_in[24];
  const float* btsv = (const float*)d_in[25];
  const float* Wm1  = (const float*)d_in[26];
  const float* bm1  = (const float*)d_in[27];
  const float* Wm2  = (const float*)d_in[28];
  const float* bm2  = (const float*)d_in[29];
  const float* Wg   = (const float*)d_in[30];
  const float* bg   = (const float*)d_in[31];
  float* out = (float*)d_out;
  float* ws  = (float*)d_ws;

  const int nrows = in_sizes[0] / 40;

  hipLaunchKernelGGL(fold_kernel, dim3(1), dim3(256), 0, stream,
                     Wiv, biv, Wtv, btv, Wisv, bisv, Wtsv, btsv,
                     Wm1, bm1, Wg, bg, ws);

  const int grid = (nrows + 255) / 256;
  hipLaunchKernelGGL(fused_main, dim3(grid), dim3(256), 0, stream,
                     img, txt, ws, Wm2, bm2, out, nrows);
}

// Round 2
// 53.837 us; speedup vs baseline: 2.9555x; 2.9555x over previous
//
#include <hip/hip_runtime.h>
#include <hip/hip_bf16.h>
#include <math.h>

typedef __attribute__((ext_vector_type(8))) short short8v;  // 8 bf16 in 4 VGPRs
typedef __attribute__((ext_vector_type(4))) float f32x4;

// ws layout (floats): three padded [48][64] weight mats + 3 bias vectors
#define WS_HA 0        // hA[48][64]: cols 0..39 img-coeff, 40..59 txt-coeff, 60..63 zero
#define WS_GA 3072     // gA[48][64]: gate coeffs, same packing
#define WS_W2 6144     // W2p[48][64]: Wm2 (K=48) zero-padded to 64
#define WS_CH 9216     // c_h[48]
#define WS_CG 9264     // c_g[48]
#define WS_B2 9312     // b2[48]
#define WS_TOTAL 9360

__device__ inline unsigned short f2bf(float f) {
  unsigned int u = __builtin_bit_cast(unsigned int, f);
  return (unsigned short)((u + 0x7FFFu + ((u >> 16) & 1u)) >> 16);  // RNE
}

__device__ inline short8v pack8(float4 a, float4 b) {
  short8v s;
  s[0] = (short)f2bf(a.x); s[1] = (short)f2bf(a.y);
  s[2] = (short)f2bf(a.z); s[3] = (short)f2bf(a.w);
  s[4] = (short)f2bf(b.x); s[5] = (short)f2bf(b.y);
  s[6] = (short)f2bf(b.z); s[7] = (short)f2bf(b.w);
  return s;
}

// Fold the linear prefix into padded bf16-ready fp32 matrices. 16 blocks x 256.
__global__ void fold_kernel(
    const float* __restrict__ Wiv, const float* __restrict__ biv,
    const float* __restrict__ Wtv, const float* __restrict__ btv,
    const float* __restrict__ Wisv, const float* __restrict__ bisv,
    const float* __restrict__ Wtsv, const float* __restrict__ btsv,
    const float* __restrict__ Wm1, const float* __restrict__ bm1,
    const float* __restrict__ Wm2, const float* __restrict__ bm2,
    const float* __restrict__ Wg, const float* __restrict__ bg,
    float* __restrict__ ws) {
  const int gid = blockIdx.x * 256 + threadIdx.x;
  const int nthr = gridDim.x * 256;

  // hA[o][j]
  for (int idx = gid; idx < 48 * 64; idx += nthr) {
    int o = idx >> 6, j = idx & 63;
    float acc = 0.f;
    if (j < 40) {
      for (int k = 0; k < 48; ++k) acc += Wm1[o * 144 + 48 + k] * Wtv[k * 40 + j];
      for (int k = 0; k < 24; ++k) acc += Wm1[o * 144 + 96 + k] * Wisv[k * 40 + j];
    } else if (j < 60) {
      int jj = j - 40;
      for (int k = 0; k < 48; ++k) acc += Wm1[o * 144 + k] * Wiv[k * 20 + jj];
      for (int k = 0; k < 24; ++k) acc += Wm1[o * 144 + 120 + k] * Wtsv[k * 20 + jj];
    }
    ws[WS_HA + idx] = acc;
  }
  // gA[o][j]
  for (int idx = gid; idx < 48 * 64; idx += nthr) {
    int o = idx >> 6, j = idx & 63;
    float acc = 0.f;
    if (j < 40) {
      for (int k = 0; k < 48; ++k) acc += Wg[o * 96 + 48 + k] * Wtv[k * 40 + j];
    } else if (j < 60) {
      int jj = j - 40;
      for (int k = 0; k < 48; ++k) acc += Wg[o * 96 + k] * Wiv[k * 20 + jj];
    }
    ws[WS_GA + idx] = acc;
  }
  // W2p[o][k]
  for (int idx = gid; idx < 48 * 64; idx += nthr) {
    int o = idx >> 6, k = idx & 63;
    ws[WS_W2 + idx] = (k < 48) ? Wm2[o * 48 + k] : 0.f;
  }
  // biases
  for (int o = gid; o < 48; o += nthr) {
    float acc = bm1[o];
    for (int k = 0; k < 48; ++k) acc += Wm1[o * 144 + k] * biv[k];
    for (int k = 0; k < 48; ++k) acc += Wm1[o * 144 + 48 + k] * btv[k];
    for (int k = 0; k < 24; ++k) acc += Wm1[o * 144 + 96 + k] * bisv[k];
    for (int k = 0; k < 24; ++k) acc += Wm1[o * 144 + 120 + k] * btsv[k];
    ws[WS_CH + o] = acc;

    float gacc = bg[o];
    for (int k = 0; k < 48; ++k) gacc += Wg[o * 96 + k] * biv[k];
    for (int k = 0; k < 48; ++k) gacc += Wg[o * 96 + 48 + k] * btv[k];
    ws[WS_CG + o] = gacc;

    ws[WS_B2 + o] = bm2[o];
  }
}

// 256 threads = 4 waves; each wave owns 64 rows = 4 MFMA tiles of 16 rows.
__global__ __launch_bounds__(256) void mfma_main(
    const float* __restrict__ img, const float* __restrict__ txt,
    const float* __restrict__ ws, float* __restrict__ out) {
  const int tid = threadIdx.x;
  const int wave = tid >> 6;
  const int lane = tid & 63;
  const int r = lane & 15;   // row (A-frag) / col (B-frag) sub-index
  const int c = lane >> 4;   // k-chunk index (8 bf16 per chunk)

  // wave-private h staging: [16 rows][72 bf16] (stride 144B breaks bank alignment)
  __shared__ __align__(16) unsigned short hlds[4][16][72];
  for (int i = tid; i < 4 * 16 * 72; i += 256) (&hlds[0][0][0])[i] = 0;

  // ---- resident weight B-fragments (lane&15 = output col, k = c*8+j) ----
  short8v wh[3][2], wg[3][2], w2[3][2];
  float bh[3], bgt[3], b2r[3];
  const float* hA = ws + WS_HA;
  const float* gA = ws + WS_GA;
  const float* W2 = ws + WS_W2;
#pragma unroll
  for (int nt = 0; nt < 3; ++nt) {
    const int col = nt * 16 + r;
#pragma unroll
    for (int f = 0; f < 2; ++f) {
      const int k0 = f * 32 + c * 8;
      wh[nt][f] = pack8(*(const float4*)(hA + col * 64 + k0),
                        *(const float4*)(hA + col * 64 + k0 + 4));
      wg[nt][f] = pack8(*(const float4*)(gA + col * 64 + k0),
                        *(const float4*)(gA + col * 64 + k0 + 4));
      w2[nt][f] = pack8(*(const float4*)(W2 + col * 64 + k0),
                        *(const float4*)(W2 + col * 64 + k0 + 4));
    }
    bh[nt] = ws[WS_CH + col];
    bgt[nt] = ws[WS_CG + col];
    b2r[nt] = ws[WS_B2 + col];
  }
  __syncthreads();  // hlds zero-pad visible to all

  const int base = blockIdx.x * 256 + wave * 64;
#pragma unroll 1
  for (int t4 = 0; t4 < 4; ++t4) {
    const int rowbase = base + t4 * 16;
    const float* pimg = img + (size_t)(rowbase + r) * 40;
    const float* ptxt = txt + (size_t)(rowbase + r) * 20;

    // ---- X A-fragments: lane&15 = batch row, k = f*32 + c*8 + j ----
    short8v xa0 = pack8(*(const float4*)(pimg + c * 8),
                        *(const float4*)(pimg + c * 8 + 4));
    short8v xa1;
    {
      float4 b0, b1;
      if (c == 0) {
        b0 = *(const float4*)(pimg + 32); b1 = *(const float4*)(pimg + 36);
      } else if (c == 3) {
        b0 = *(const float4*)(ptxt + 16); b1 = make_float4(0.f, 0.f, 0.f, 0.f);
      } else {
        b0 = *(const float4*)(ptxt + (c - 1) * 8);
        b1 = *(const float4*)(ptxt + (c - 1) * 8 + 4);
      }
      xa1 = pack8(b0, b1);
    }

    // ---- h = relu(X @ hA^T + c_h) ----
    f32x4 hacc[3];
#pragma unroll
    for (int nt = 0; nt < 3; ++nt) {
      f32x4 a; a[0] = bh[nt]; a[1] = bh[nt]; a[2] = bh[nt]; a[3] = bh[nt];
      a = __builtin_amdgcn_mfma_f32_16x16x32_bf16(xa0, wh[nt][0], a, 0, 0, 0);
      a = __builtin_amdgcn_mfma_f32_16x16x32_bf16(xa1, wh[nt][1], a, 0, 0, 0);
      hacc[nt] = a;
    }
    // store h to LDS in bf16 (D layout: row = c*4+j, col = nt*16+r)
#pragma unroll
    for (int nt = 0; nt < 3; ++nt)
#pragma unroll
      for (int j = 0; j < 4; ++j)
        hlds[wave][c * 4 + j][nt * 16 + r] = f2bf(fmaxf(hacc[nt][j], 0.f));

    // ---- gate preact (reuses X frags, no LDS dependency) ----
    f32x4 gacc[3];
#pragma unroll
    for (int nt = 0; nt < 3; ++nt) {
      f32x4 a; a[0] = bgt[nt]; a[1] = bgt[nt]; a[2] = bgt[nt]; a[3] = bgt[nt];
      a = __builtin_amdgcn_mfma_f32_16x16x32_bf16(xa0, wg[nt][0], a, 0, 0, 0);
      a = __builtin_amdgcn_mfma_f32_16x16x32_bf16(xa1, wg[nt][1], a, 0, 0, 0);
      gacc[nt] = a;
    }

    __syncthreads();  // h writes visible (also keeps waves in lockstep)

    // ---- fused = relu(h @ W2^T + b2): h A-frags from LDS ----
    short8v ha0 = *(const short8v*)&hlds[wave][r][c * 8];
    short8v ha1 = *(const short8v*)&hlds[wave][r][32 + c * 8];
    f32x4 oacc[3];
#pragma unroll
    for (int nt = 0; nt < 3; ++nt) {
      f32x4 a; a[0] = b2r[nt]; a[1] = b2r[nt]; a[2] = b2r[nt]; a[3] = b2r[nt];
      a = __builtin_amdgcn_mfma_f32_16x16x32_bf16(ha0, w2[nt][0], a, 0, 0, 0);
      a = __builtin_amdgcn_mfma_f32_16x16x32_bf16(ha1, w2[nt][1], a, 0, 0, 0);
      oacc[nt] = a;
    }

    // ---- out = relu(fused) * sigmoid(gate) ----
#pragma unroll
    for (int nt = 0; nt < 3; ++nt) {
#pragma unroll
      for (int j = 0; j < 4; ++j) {
        float fz = fmaxf(oacc[nt][j], 0.f);
        float g = 1.f / (1.f + __expf(-gacc[nt][j]));
        out[(size_t)(rowbase + c * 4 + j) * 48 + nt * 16 + r] = fz * g;
      }
    }
    __syncthreads();  // WAR: next tile's h-writes vs this tile's reads (cross-wave lockstep)
  }
}

extern "C" void kernel_launch(void* const* d_in, const int* in_sizes, int n_in,
                              void* d_out, int out_size, void* d_ws, size_t ws_size,
                              hipStream_t stream) {
  const float* img  = (const float*)d_in[0];
  const float* txt  = (const float*)d_in[1];
  const float* Wiv  = (const float*)d_in[6];
  const float* biv  = (const float*)d_in[7];
  const float* Wtv  = (const float*)d_in[12];
  const float* btv  = (const float*)d_in[13];
  const float* Wisv = (const float*)d_in[18];
  const float* bisv = (const float*)d_in[19];
  const float* Wtsv = (const float*)d_in[24];
  const float* btsv = (const float*)d_in[25];
  const float* Wm1  = (const float*)d_in[26];
  const float* bm1  = (const float*)d_in[27];
  const float* Wm2  = (const float*)d_in[28];
  const float* bm2  = (const float*)d_in[29];
  const float* Wg   = (const float*)d_in[30];
  const float* bg   = (const float*)d_in[31];
  float* out = (float*)d_out;
  float* ws  = (float*)d_ws;

  const int nrows = in_sizes[0] / 40;  // 262144

  hipLaunchKernelGGL(fold_kernel, dim3(16), dim3(256), 0, stream,
                     Wiv, biv, Wtv, btv, Wisv, bisv, Wtsv, btsv,
                     Wm1, bm1, Wm2, bm2, Wg, bg, ws);

  const int grid = nrows / 256;  // B divisible by 256
  hipLaunchKernelGGL(mfma_main, dim3(grid), dim3(256), 0, stream,
                     img, txt, ws, out);
}

// Round 4
// 47.327 us; speedup vs baseline: 3.3620x; 1.1376x over previous
//
#include <hip/hip_runtime.h>
#include <hip/hip_bf16.h>
#include <math.h>

typedef __attribute__((ext_vector_type(8))) short short8v;  // 8 bf16 in 4 VGPRs
typedef __attribute__((ext_vector_type(4))) float f32x4;

// ws layout (floats)
#define WS_HA 0        // hA[48][64]: k 0..39 img, 40..59 txt, 60 = c_h (bias), 61..63 zero
#define WS_GA 3072     // gA[48][64]: gate coeffs, k60 = c_g
#define WS_W2 6144     // W2p[48][64]: Wm2 zero-padded
#define WS_B2 9216     // b2[48]
#define WS_TOTAL 9264

__device__ inline unsigned short f2bf(float f) {
  return __builtin_bit_cast(unsigned short, __float2bfloat16(f));
}

__device__ inline short8v pack8(float4 a, float4 b) {
  short8v s;
  s[0] = (short)f2bf(a.x); s[1] = (short)f2bf(a.y);
  s[2] = (short)f2bf(a.z); s[3] = (short)f2bf(a.w);
  s[4] = (short)f2bf(b.x); s[5] = (short)f2bf(b.y);
  s[6] = (short)f2bf(b.z); s[7] = (short)f2bf(b.w);
  return s;
}

// Fold linear prefix into padded weight mats; biases go into the k=60 slot
// (consumed by a constant-1.0 input there). Each ws slot written exactly once.
__global__ void fold_kernel(
    const float* __restrict__ Wiv, const float* __restrict__ biv,
    const float* __restrict__ Wtv, const float* __restrict__ btv,
    const float* __restrict__ Wisv, const float* __restrict__ bisv,
    const float* __restrict__ Wtsv, const float* __restrict__ btsv,
    const float* __restrict__ Wm1, const float* __restrict__ bm1,
    const float* __restrict__ Wm2, const float* __restrict__ bm2,
    const float* __restrict__ Wg, const float* __restrict__ bg,
    float* __restrict__ ws) {
  const int gid = blockIdx.x * 256 + threadIdx.x;
  const int nthr = gridDim.x * 256;

  for (int idx = gid; idx < 48 * 64; idx += nthr) {
    int o = idx >> 6, j = idx & 63;
    if (j == 60) continue;  // bias slot, written below
    float acc = 0.f;
    if (j < 40) {
      for (int k = 0; k < 48; ++k) acc += Wm1[o * 144 + 48 + k] * Wtv[k * 40 + j];
      for (int k = 0; k < 24; ++k) acc += Wm1[o * 144 + 96 + k] * Wisv[k * 40 + j];
    } else if (j < 60) {
      int jj = j - 40;
      for (int k = 0; k < 48; ++k) acc += Wm1[o * 144 + k] * Wiv[k * 20 + jj];
      for (int k = 0; k < 24; ++k) acc += Wm1[o * 144 + 120 + k] * Wtsv[k * 20 + jj];
    }
    ws[WS_HA + idx] = acc;
  }
  for (int idx = gid; idx < 48 * 64; idx += nthr) {
    int o = idx >> 6, j = idx & 63;
    if (j == 60) continue;
    float acc = 0.f;
    if (j < 40) {
      for (int k = 0; k < 48; ++k) acc += Wg[o * 96 + 48 + k] * Wtv[k * 40 + j];
    } else if (j < 60) {
      int jj = j - 40;
      for (int k = 0; k < 48; ++k) acc += Wg[o * 96 + k] * Wiv[k * 20 + jj];
    }
    ws[WS_GA + idx] = acc;
  }
  for (int idx = gid; idx < 48 * 64; idx += nthr) {
    int o = idx >> 6, k = idx & 63;
    ws[WS_W2 + idx] = (k < 48) ? Wm2[o * 48 + k] : 0.f;
  }
  for (int o = gid; o < 48; o += nthr) {
    float acc = bm1[o];
    for (int k = 0; k < 48; ++k) acc += Wm1[o * 144 + k] * biv[k];
    for (int k = 0; k < 48; ++k) acc += Wm1[o * 144 + 48 + k] * btv[k];
    for (int k = 0; k < 24; ++k) acc += Wm1[o * 144 + 96 + k] * bisv[k];
    for (int k = 0; k < 24; ++k) acc += Wm1[o * 144 + 120 + k] * btsv[k];
    ws[WS_HA + o * 64 + 60] = acc;

    float gacc = bg[o];
    for (int k = 0; k < 48; ++k) gacc += Wg[o * 96 + k] * biv[k];
    for (int k = 0; k < 48; ++k) gacc += Wg[o * 96 + 48 + k] * btv[k];
    ws[WS_GA + o * 64 + 60] = gacc;

    ws[WS_B2 + o] = bm2[o];
  }
}

// All GEMMs transposed: weights as A-fragments (lane&15 = output dim),
// X / h^T as B-fragments (lane&15 = batch). h flows acc -> relu -> bf16 pack
// -> next MFMA entirely in-register via the delta k-permutation. No LDS,
// no barriers; waves fully independent streaming.
__global__ __launch_bounds__(256) void mfma_main(
    const float* __restrict__ img, const float* __restrict__ txt,
    const float* __restrict__ ws, float* __restrict__ out) {
  const int tid = threadIdx.x;
  const int wave = tid >> 6;
  const int lane = tid & 63;
  const int r = lane & 15;   // A: output-dim sub-row | B/D: batch col
  const int c = lane >> 4;   // k-chunk / D reg-group row

  // ---- resident weight A-fragments ----
  short8v hAf[3][2], gAf[3][2], w2f[3][2];
  const float* hA = ws + WS_HA;
  const float* gA = ws + WS_GA;
  const float* W2 = ws + WS_W2;
#pragma unroll
  for (int go = 0; go < 3; ++go) {
    const int row = go * 16 + r;
#pragma unroll
    for (int f = 0; f < 2; ++f) {
      const int k0 = f * 32 + c * 8;
      hAf[go][f] = pack8(*(const float4*)(hA + row * 64 + k0),
                         *(const float4*)(hA + row * 64 + k0 + 4));
      gAf[go][f] = pack8(*(const float4*)(gA + row * 64 + k0),
                         *(const float4*)(gA + row * 64 + k0 + 4));
    }
    // delta-permuted W2: frag0 = dims {4c+j, 16+4c+j}, frag1 = {32+4c+j, b2, 0..}
    w2f[go][0] = pack8(*(const float4*)(W2 + row * 64 + 4 * c),
                       *(const float4*)(W2 + row * 64 + 16 + 4 * c));
    w2f[go][1] = pack8(*(const float4*)(W2 + row * 64 + 32 + 4 * c),
                       make_float4(ws[WS_B2 + row], 0.f, 0.f, 0.f));
  }

  const int base = blockIdx.x * 256 + wave * 64;
  const f32x4 z = {0.f, 0.f, 0.f, 0.f};

#pragma unroll 1
  for (int t4 = 0; t4 < 4; ++t4) {
    const int rowbase = base + t4 * 16;
    const float* pimg = img + (size_t)(rowbase + r) * 40;
    const float* ptxt = txt + (size_t)(rowbase + r) * 20;

    // X B-fragment: lane&15 = batch, k = f*32 + c*8 + jj; k60 = 1.0 (bias input)
    float4 i0 = *(const float4*)(pimg + c * 8);
    float4 i1 = *(const float4*)(pimg + c * 8 + 4);
    float4 b0, b1;
    if (c == 0) {
      b0 = *(const float4*)(pimg + 32); b1 = *(const float4*)(pimg + 36);
    } else if (c == 3) {
      b0 = *(const float4*)(ptxt + 16); b1 = make_float4(1.f, 0.f, 0.f, 0.f);
    } else {
      b0 = *(const float4*)(ptxt + (c - 1) * 8);
      b1 = *(const float4*)(ptxt + (c - 1) * 8 + 4);
    }
    short8v xa0 = pack8(i0, i1);
    short8v xa1 = pack8(b0, b1);

    // h^T = W_h X  (D: col=batch, row-regs = h-dims 16*go + 4c + j)
    f32x4 hacc[3], gacc[3];
#pragma unroll
    for (int go = 0; go < 3; ++go)
      hacc[go] = __builtin_amdgcn_mfma_f32_16x16x32_bf16(
          hAf[go][1], xa1,
          __builtin_amdgcn_mfma_f32_16x16x32_bf16(hAf[go][0], xa0, z, 0, 0, 0),
          0, 0, 0);
#pragma unroll
    for (int go = 0; go < 3; ++go)
      gacc[go] = __builtin_amdgcn_mfma_f32_16x16x32_bf16(
          gAf[go][1], xa1,
          __builtin_amdgcn_mfma_f32_16x16x32_bf16(gAf[go][0], xa0, z, 0, 0, 0),
          0, 0, 0);

    // relu(h) -> bf16 B-fragments in delta order (no cross-lane movement!)
    short8v hb0, hb1;
#pragma unroll
    for (int j = 0; j < 4; ++j) {
      hb0[j]     = (short)f2bf(fmaxf(hacc[0][j], 0.f));
      hb0[j + 4] = (short)f2bf(fmaxf(hacc[1][j], 0.f));
      hb1[j]     = (short)f2bf(fmaxf(hacc[2][j], 0.f));
    }
    // bias-1.0 ONLY in the c==3 lane group: exactly one k-slot carries the
    // bias (round-3 bug: all four c groups carried it -> 4x bias).
    hb1[4] = (c == 3) ? (short)0x3F80 : (short)0;
    hb1[5] = 0; hb1[6] = 0; hb1[7] = 0;

    // fused^T = W2 h^T
    f32x4 oacc[3];
#pragma unroll
    for (int go = 0; go < 3; ++go)
      oacc[go] = __builtin_amdgcn_mfma_f32_16x16x32_bf16(
          w2f[go][1], hb1,
          __builtin_amdgcn_mfma_f32_16x16x32_bf16(w2f[go][0], hb0, z, 0, 0, 0),
          0, 0, 0);

    // out[batch=r][o = 16*go + 4c + j] — j consecutive -> float4 stores
    float* orow = out + (size_t)(rowbase + r) * 48;
#pragma unroll
    for (int go = 0; go < 3; ++go) {
      float4 v;
      v.x = fmaxf(oacc[go][0], 0.f) * (1.f / (1.f + __expf(-gacc[go][0])));
      v.y = fmaxf(oacc[go][1], 0.f) * (1.f / (1.f + __expf(-gacc[go][1])));
      v.z = fmaxf(oacc[go][2], 0.f) * (1.f / (1.f + __expf(-gacc[go][2])));
      v.w = fmaxf(oacc[go][3], 0.f) * (1.f / (1.f + __expf(-gacc[go][3])));
      *reinterpret_cast<float4*>(orow + 16 * go + 4 * c) = v;
    }
  }
}

extern "C" void kernel_launch(void* const* d_in, const int* in_sizes, int n_in,
                              void* d_out, int out_size, void* d_ws, size_t ws_size,
                              hipStream_t stream) {
  const float* img  = (const float*)d_in[0];
  const float* txt  = (const float*)d_in[1];
  const float* Wiv  = (const float*)d_in[6];
  const float* biv  = (const float*)d_in[7];
  const float* Wtv  = (const float*)d_in[12];
  const float* btv  = (const float*)d_in[13];
  const float* Wisv = (const float*)d_in[18];
  const float* bisv = (const float*)d_in[19];
  const float* Wtsv = (const float*)d_in[24];
  const float* btsv = (const float*)d_in[25];
  const float* Wm1  = (const float*)d_in[26];
  const float* bm1  = (const float*)d_in[27];
  const float* Wm2  = (const float*)d_in[28];
  const float* bm2  = (const float*)d_in[29];
  const float* Wg   = (const float*)d_in[30];
  const float* bg   = (const float*)d_in[31];
  float* out = (float*)d_out;
  float* ws  = (float*)d_ws;

  const int nrows = in_sizes[0] / 40;  // 262144

  hipLaunchKernelGGL(fold_kernel, dim3(32), dim3(256), 0, stream,
                     Wiv, biv, Wtv, btv, Wisv, bisv, Wtsv, btsv,
                     Wm1, bm1, Wm2, bm2, Wg, bg, ws);

  const int grid = nrows / 256;  // 1024 blocks x 4 waves, 64 rows/wave
  hipLaunchKernelGGL(mfma_main, dim3(grid), dim3(256), 0, stream,
                     img, txt, ws, out);
}